// Round 1
// baseline (3277.977 us; speedup 1.0000x reference)
//
#include <hip/hip_runtime.h>
#include <math.h>

// ---------------------------------------------------------------------------
// Shapes (hardcoded from reference): T=128, N=32 -> TN=4096
//  x:      (4096, 4, 64, 64) f32
//  conv1:  (32,4,8,8)  s4 -> a1 (4096,32,15,15)
//  conv2:  (64,32,4,4) s2 -> a2 (4096,64,6,6)
//  conv3:  (64,64,3,3) s1 -> a3 (4096,64,4,4) == (4096,1024)
//  fc:     (512,1024)      -> feats (4096,512)
//  lstm:   wi (1024,512), wh (1024,256), H=256
//  heads:  actor (18,256), critic (1,256) -> out (4096,19)
// ---------------------------------------------------------------------------

#define TN 4096

// ---- conv1: one thread computes 8 output channels for one (n, oy, ox) ----
__global__ __launch_bounds__(256) void conv1_kernel(
    const float* __restrict__ x, const float* __restrict__ w,
    const float* __restrict__ bias, float* __restrict__ out) {
  int tid = blockIdx.x * 256 + threadIdx.x;        // 4096*4*225 = 3,686,400
  int n = tid / 900;
  int r = tid - n * 900;
  int g = r / 225;                                  // oc group (0..3), oc = g*8+o
  int p = r - g * 225;
  int oy = p / 15, ox = p - oy * 15;

  float acc[8] = {0.f,0.f,0.f,0.f,0.f,0.f,0.f,0.f};
  const float* xb = x + n * (4 * 64 * 64);
  const float* wb = w + g * 8 * 256;                // oc stride = 4*8*8 = 256

  for (int c = 0; c < 4; ++c) {
    #pragma unroll
    for (int ky = 0; ky < 8; ++ky) {
      const float* xr = xb + (c * 64 + 4 * oy + ky) * 64 + 4 * ox;
      float4 x0 = *(const float4*)(xr);
      float4 x1 = *(const float4*)(xr + 4);
      const float* wr = wb + (c * 8 + ky) * 8;
      #pragma unroll
      for (int o = 0; o < 8; ++o) {
        float4 w0 = *(const float4*)(wr + o * 256);
        float4 w1 = *(const float4*)(wr + o * 256 + 4);
        float s = acc[o];
        s = fmaf(x0.x, w0.x, s); s = fmaf(x0.y, w0.y, s);
        s = fmaf(x0.z, w0.z, s); s = fmaf(x0.w, w0.w, s);
        s = fmaf(x1.x, w1.x, s); s = fmaf(x1.y, w1.y, s);
        s = fmaf(x1.z, w1.z, s); s = fmaf(x1.w, w1.w, s);
        acc[o] = s;
      }
    }
  }
  const float inv255 = (1.f / 255.f);
  #pragma unroll
  for (int o = 0; o < 8; ++o) {
    int oc = g * 8 + o;
    float v = acc[o] * inv255 + bias[oc];
    out[(n * 32 + oc) * 225 + p] = fmaxf(v, 0.f);
  }
}

// ---- conv2: 8 ocs per thread, input (4096,32,15,15) ----
__global__ __launch_bounds__(256) void conv2_kernel(
    const float* __restrict__ a1, const float* __restrict__ w,
    const float* __restrict__ bias, float* __restrict__ out) {
  int tid = blockIdx.x * 256 + threadIdx.x;        // 4096*8*36 = 1,179,648
  int n = tid / 288;
  int r = tid - n * 288;
  int g = r / 36;                                   // oc group (0..7)
  int p = r - g * 36;
  int oy = p / 6, ox = p - oy * 6;

  float acc[8] = {0.f,0.f,0.f,0.f,0.f,0.f,0.f,0.f};
  const float* ab = a1 + n * (32 * 225);
  const float* wb = w + g * 8 * 512;                // oc stride = 32*4*4 = 512

  for (int c = 0; c < 32; ++c) {
    #pragma unroll
    for (int ky = 0; ky < 4; ++ky) {
      const float* xr = ab + c * 225 + (2 * oy + ky) * 15 + 2 * ox;
      float x0 = xr[0], x1 = xr[1], x2 = xr[2], x3 = xr[3];
      const float* wr = wb + c * 16 + ky * 4;
      #pragma unroll
      for (int o = 0; o < 8; ++o) {
        float4 wv = *(const float4*)(wr + o * 512);
        acc[o] = fmaf(x0, wv.x, fmaf(x1, wv.y, fmaf(x2, wv.z, fmaf(x3, wv.w, acc[o]))));
      }
    }
  }
  #pragma unroll
  for (int o = 0; o < 8; ++o) {
    int oc = g * 8 + o;
    out[(n * 64 + oc) * 36 + p] = fmaxf(acc[o] + bias[oc], 0.f);
  }
}

// ---- conv3: 8 ocs per thread, input (4096,64,6,6) ----
__global__ __launch_bounds__(256) void conv3_kernel(
    const float* __restrict__ a2, const float* __restrict__ w,
    const float* __restrict__ bias, float* __restrict__ out) {
  int tid = blockIdx.x * 256 + threadIdx.x;        // 4096*8*16 = 524,288
  int n = tid / 128;
  int r = tid - n * 128;
  int g = r / 16;
  int p = r - g * 16;
  int oy = p / 4, ox = p - oy * 4;

  float acc[8] = {0.f,0.f,0.f,0.f,0.f,0.f,0.f,0.f};
  const float* ab = a2 + n * (64 * 36);
  const float* wb = w + g * 8 * 576;                // oc stride = 64*9

  for (int c = 0; c < 64; ++c) {
    const float* xr = ab + c * 36 + oy * 6 + ox;
    float xv[9];
    #pragma unroll
    for (int ky = 0; ky < 3; ++ky)
      #pragma unroll
      for (int kx = 0; kx < 3; ++kx)
        xv[ky * 3 + kx] = xr[ky * 6 + kx];
    const float* wr = wb + c * 9;
    #pragma unroll
    for (int o = 0; o < 8; ++o) {
      const float* wo = wr + o * 576;
      float s = acc[o];
      #pragma unroll
      for (int q = 0; q < 9; ++q) s = fmaf(xv[q], wo[q], s);
      acc[o] = s;
    }
  }
  #pragma unroll
  for (int o = 0; o < 8; ++o) {
    int oc = g * 8 + o;
    out[(n * 64 + oc) * 16 + p] = fmaxf(acc[o] + bias[oc], 0.f);
  }
}

// ---- generic GEMM: C[M,N] = act(A[M,K] @ B[N,K]^T + bias1 (+bias2)) ----
// 64x64 tile, 256 threads, 4x4 microtile, BK=16.
__global__ __launch_bounds__(256) void gemm_bias_kernel(
    const float* __restrict__ A, const float* __restrict__ B,
    const float* __restrict__ bias1, const float* __restrict__ bias2,
    float* __restrict__ C, int M, int N, int K, int relu) {
  __shared__ float As[16][68];
  __shared__ float Bs[16][68];
  const int t = threadIdx.x;
  const int n0 = blockIdx.x * 64;
  const int m0 = blockIdx.y * 64;
  const int ty = t >> 4, tx = t & 15;
  const int sl = t >> 2, kq = (t & 3) * 4;

  float acc[4][4] = {};

  for (int k0 = 0; k0 < K; k0 += 16) {
    float4 av = *(const float4*)(A + (size_t)(m0 + sl) * K + k0 + kq);
    float4 bv = *(const float4*)(B + (size_t)(n0 + sl) * K + k0 + kq);
    As[kq + 0][sl] = av.x; As[kq + 1][sl] = av.y;
    As[kq + 2][sl] = av.z; As[kq + 3][sl] = av.w;
    Bs[kq + 0][sl] = bv.x; Bs[kq + 1][sl] = bv.y;
    Bs[kq + 2][sl] = bv.z; Bs[kq + 3][sl] = bv.w;
    __syncthreads();
    #pragma unroll
    for (int kk = 0; kk < 16; ++kk) {
      float4 a = *(const float4*)&As[kk][ty * 4];
      float4 b = *(const float4*)&Bs[kk][tx * 4];
      float ar[4] = {a.x, a.y, a.z, a.w};
      float br[4] = {b.x, b.y, b.z, b.w};
      #pragma unroll
      for (int i = 0; i < 4; ++i)
        #pragma unroll
        for (int j = 0; j < 4; ++j)
          acc[i][j] = fmaf(ar[i], br[j], acc[i][j]);
    }
    __syncthreads();
  }

  #pragma unroll
  for (int i = 0; i < 4; ++i) {
    int m = m0 + ty * 4 + i;
    #pragma unroll
    for (int j = 0; j < 4; ++j) {
      int n = n0 + tx * 4 + j;
      float v = acc[i][j] + bias1[n];
      if (bias2) v += bias2[n];
      if (relu) v = fmaxf(v, 0.f);
      C[(size_t)m * N + n] = v;
    }
  }
}

// ---- LSTM step: 128 blocks x 256 thr; block bk owns hidden units {2bk, 2bk+1}.
// thread t: b = t&31, gate g = (t>>5)&3, jj = t>>7. One 256-long dot each.
__global__ __launch_bounds__(256) void lstm_step_kernel(
    const float* __restrict__ gates_pre, const float* __restrict__ wh,
    const float* __restrict__ done, const float* __restrict__ h_prev,
    const float* __restrict__ c_src, float* __restrict__ c_ws,
    float* __restrict__ outs, int step) {
  __shared__ float hs[256 * 33];  // hs[k*33 + b] = h_prev[b][k] * m[b]
  __shared__ float gb[256];
  const int t = threadIdx.x;
  const int bk = blockIdx.x;

  // stage masked h (transpose through padded LDS; conflict-free both ways)
  for (int i = 0; i < 32; ++i) {
    float m = 1.f - done[step * 32 + i];
    hs[t * 33 + i] = h_prev[i * 256 + t] * m;
  }
  __syncthreads();

  const int b = t & 31;
  const int g = (t >> 5) & 3;
  const int jj = t >> 7;
  const int j = bk * 2 + jj;
  const int grow = g * 256 + j;
  const float* whr = wh + grow * 256;

  float a0 = 0.f, a1 = 0.f, a2 = 0.f, a3 = 0.f;
  for (int k = 0; k < 256; k += 4) {
    a0 = fmaf(hs[(k + 0) * 33 + b], whr[k + 0], a0);
    a1 = fmaf(hs[(k + 1) * 33 + b], whr[k + 1], a1);
    a2 = fmaf(hs[(k + 2) * 33 + b], whr[k + 2], a2);
    a3 = fmaf(hs[(k + 3) * 33 + b], whr[k + 3], a3);
  }
  float gate = (a0 + a1) + (a2 + a3) + gates_pre[(size_t)(step * 32 + b) * 1024 + grow];
  gb[g * 64 + jj * 32 + b] = gate;
  __syncthreads();

  if (t < 64) {
    int b2 = t & 31, jj2 = t >> 5;
    int j2 = bk * 2 + jj2;
    float iv = gb[0   + jj2 * 32 + b2];
    float fv = gb[64  + jj2 * 32 + b2];
    float gv = gb[128 + jj2 * 32 + b2];
    float ov = gb[192 + jj2 * 32 + b2];
    float m = 1.f - done[step * 32 + b2];
    float c_old = c_src[b2 * 256 + j2] * m;
    float ig = 1.f / (1.f + expf(-iv));
    float fg = 1.f / (1.f + expf(-fv));
    float og = 1.f / (1.f + expf(-ov));
    float cn = fmaf(fg, c_old, ig * tanhf(gv));
    float hn = og * tanhf(cn);
    c_ws[b2 * 256 + j2] = cn;
    outs[(size_t)(step * 32 + b2) * 256 + j2] = hn;
  }
}

// ---- heads: out[r,0:18] = actor, out[r,18] = critic; 8 rows per block ----
__global__ __launch_bounds__(256) void heads_kernel(
    const float* __restrict__ outs, const float* __restrict__ aw,
    const float* __restrict__ ab, const float* __restrict__ cw,
    const float* __restrict__ cb, float* __restrict__ out) {
  __shared__ float rs[8 * 256];
  const int t = threadIdx.x;
  const int r0 = blockIdx.x * 8;
  for (int i = 0; i < 8; ++i)
    rs[i * 256 + t] = outs[(size_t)(r0 + i) * 256 + t];
  __syncthreads();
  int r = t >> 5, c = t & 31;
  if (c < 19) {
    const float* wr = (c < 18) ? (aw + c * 256) : cw;
    float bias = (c < 18) ? ab[c] : cb[0];
    float acc = 0.f;
    for (int k = 0; k < 256; ++k) acc = fmaf(rs[r * 256 + k], wr[k], acc);
    out[(size_t)(r0 + r) * 19 + c] = acc + bias;
  }
}

extern "C" void kernel_launch(void* const* d_in, const int* in_sizes, int n_in,
                              void* d_out, int out_size, void* d_ws, size_t ws_size,
                              hipStream_t stream) {
  const float* x    = (const float*)d_in[0];
  const float* done = (const float*)d_in[1];
  const float* h0   = (const float*)d_in[2];
  const float* c0   = (const float*)d_in[3];
  const float* w1   = (const float*)d_in[4];
  const float* b1   = (const float*)d_in[5];
  const float* w2   = (const float*)d_in[6];
  const float* b2   = (const float*)d_in[7];
  const float* w3   = (const float*)d_in[8];
  const float* b3   = (const float*)d_in[9];
  const float* fcw  = (const float*)d_in[10];
  const float* fcb  = (const float*)d_in[11];
  const float* wi   = (const float*)d_in[12];
  const float* wh   = (const float*)d_in[13];
  const float* bi   = (const float*)d_in[14];
  const float* bh   = (const float*)d_in[15];
  const float* aw   = (const float*)d_in[16];
  const float* abv  = (const float*)d_in[17];
  const float* cw   = (const float*)d_in[18];
  const float* cbv  = (const float*)d_in[19];
  float* out = (float*)d_out;

  // workspace layout (floats)
  const size_t SZ_A1 = 29491200, SZ_A2 = 9437184, SZ_A3 = 4194304;
  const size_t SZ_F = 2097152, SZ_G = 4194304, SZ_O = 1048576, SZ_C = 8192;
  const size_t need = (SZ_A1 + SZ_A2 + SZ_A3 + SZ_F + SZ_G + SZ_O + SZ_C) * 4;
  if (ws_size < need) return;  // would corrupt memory otherwise; fail validation cleanly

  float* wsp  = (float*)d_ws;
  float* a1   = wsp;
  float* a2   = a1 + SZ_A1;
  float* a3   = a2 + SZ_A2;
  float* feats= a3 + SZ_A3;
  float* gts  = feats + SZ_F;
  float* outs = gts + SZ_G;
  float* cbuf = outs + SZ_O;

  conv1_kernel<<<14400, 256, 0, stream>>>(x, w1, b1, a1);
  conv2_kernel<<<4608, 256, 0, stream>>>(a1, w2, b2, a2);
  conv3_kernel<<<2048, 256, 0, stream>>>(a2, w3, b3, a3);
  // feats = relu(a3 @ fc_w^T + fc_b)
  gemm_bias_kernel<<<dim3(8, 64), 256, 0, stream>>>(a3, fcw, fcb, nullptr, feats,
                                                    4096, 512, 1024, 1);
  // gates_pre = feats @ wi^T + bi + bh
  gemm_bias_kernel<<<dim3(16, 64), 256, 0, stream>>>(feats, wi, bi, bh, gts,
                                                     4096, 1024, 512, 0);
  for (int t = 0; t < 128; ++t) {
    const float* hp = (t == 0) ? h0 : (outs + (size_t)(t - 1) * 8192);
    const float* cs = (t == 0) ? c0 : cbuf;
    lstm_step_kernel<<<128, 256, 0, stream>>>(gts, wh, done, hp, cs, cbuf, outs, t);
  }
  heads_kernel<<<512, 256, 0, stream>>>(outs, aw, abv, cw, cbv, out);
}

// Round 2
// 2700.444 us; speedup vs baseline: 1.2139x; 1.2139x over previous
//
#include <hip/hip_runtime.h>
#include <math.h>

// ---------------------------------------------------------------------------
// Shapes: T=128, N=32 -> TN=4096
//  x:      (4096, 4, 64, 64) f32
//  conv1:  (32,4,8,8)  s4 -> a1 (4096,32,15,15)
//  conv2:  (64,32,4,4) s2 -> a2 (4096,64,6,6)
//  conv3:  (64,64,3,3) s1 -> a3 (4096,64,4,4) == (4096,1024)
//  fc:     (512,1024)      -> feats (4096,512)
//  lstm:   wi (1024,512), wh (1024,256), H=256
//  heads:  actor (18,256), critic (1,256) -> out (4096,19)
// ---------------------------------------------------------------------------

__device__ inline float dot8(float4 a, float4 b, float4 wa, float4 wb, float s) {
  s = fmaf(a.x, wa.x, s); s = fmaf(a.y, wa.y, s);
  s = fmaf(a.z, wa.z, s); s = fmaf(a.w, wa.w, s);
  s = fmaf(b.x, wb.x, s); s = fmaf(b.y, wb.y, s);
  s = fmaf(b.z, wb.z, s); s = fmaf(b.w, wb.w, s);
  return s;
}

// ---- conv1 v2: block = one frame; thread = (oy 0..14, oc-pair 0..15).
// Thread computes a full 15-wide output row for 2 ocs. x row read as 16 float4
// (lanes w/ same oy share addresses -> L1 merge); weights hoisted: 4 float4/(c,ky).
__global__ __launch_bounds__(256, 4) void conv1_kernel(
    const float* __restrict__ x, const float* __restrict__ w,
    const float* __restrict__ bias, float* __restrict__ out) {
  const int n = blockIdx.x;
  const int t = threadIdx.x;
  const int oy = t >> 4;     // 0..15 (15 idle)
  const int og = t & 15;
  if (oy >= 15) return;
  const int oc0 = og * 2;

  float acc[15][2] = {};
  const float* xb = x + (size_t)n * 16384;
  const float* wb = w + oc0 * 256;   // oc stride 4*8*8=256

  for (int c = 0; c < 4; ++c) {
    for (int ky = 0; ky < 8; ++ky) {
      const float* xr = xb + (c * 64 + 4 * oy + ky) * 64;
      const float* wr = wb + c * 64 + ky * 8;
      const float4 w00 = *(const float4*)(wr);
      const float4 w01 = *(const float4*)(wr + 4);
      const float4 w10 = *(const float4*)(wr + 256);
      const float4 w11 = *(const float4*)(wr + 260);
      // first half: p=0..7 uses x4[0..8]
      {
        float4 xv[9];
        #pragma unroll
        for (int i = 0; i < 9; ++i) xv[i] = *(const float4*)(xr + 4 * i);
        #pragma unroll
        for (int p = 0; p < 8; ++p) {
          acc[p][0] = dot8(xv[p], xv[p + 1], w00, w01, acc[p][0]);
          acc[p][1] = dot8(xv[p], xv[p + 1], w10, w11, acc[p][1]);
        }
      }
      // second half: p=8..14 uses x4[8..15]
      {
        float4 yv[8];
        #pragma unroll
        for (int i = 0; i < 8; ++i) yv[i] = *(const float4*)(xr + 32 + 4 * i);
        #pragma unroll
        for (int p = 8; p < 15; ++p) {
          acc[p][0] = dot8(yv[p - 8], yv[p - 7], w00, w01, acc[p][0]);
          acc[p][1] = dot8(yv[p - 8], yv[p - 7], w10, w11, acc[p][1]);
        }
      }
    }
  }
  const float inv = 1.f / 255.f;
  #pragma unroll
  for (int o = 0; o < 2; ++o) {
    const int oc = oc0 + o;
    const float bb = bias[oc];
    float* orow = out + ((size_t)n * 32 + oc) * 225 + oy * 15;
    #pragma unroll
    for (int p = 0; p < 15; ++p)
      orow[p] = fmaxf(fmaf(acc[p][o], inv, bb), 0.f);
  }
}

// ---- conv2 v2: block = one frame (192 thr); thread = (oy 0..5, oc-pair 0..31).
// Thread computes 6-wide output row x 2 ocs; x row = 14 scalars (2 distinct
// oy/wave -> L1 merge), weights 2 float4/(c,ky).
__global__ __launch_bounds__(192) void conv2_kernel(
    const float* __restrict__ a1, const float* __restrict__ w,
    const float* __restrict__ bias, float* __restrict__ out) {
  const int n = blockIdx.x;
  const int t = threadIdx.x;     // 0..191
  const int oy = t >> 5;         // 0..5
  const int op = t & 31;
  const int oc0 = op * 2;

  float acc[6][2] = {};
  const float* ab = a1 + (size_t)n * 7200;
  const float* wb = w + oc0 * 512;   // oc stride 32*4*4=512

  for (int c = 0; c < 32; ++c) {
    #pragma unroll
    for (int ky = 0; ky < 4; ++ky) {
      const float* xr = ab + c * 225 + (2 * oy + ky) * 15;
      float xv[14];
      #pragma unroll
      for (int i = 0; i < 14; ++i) xv[i] = xr[i];
      const float* wr = wb + c * 16 + ky * 4;
      const float4 w0 = *(const float4*)(wr);
      const float4 w1 = *(const float4*)(wr + 512);
      #pragma unroll
      for (int p = 0; p < 6; ++p) {
        const int b = 2 * p;
        float s0 = acc[p][0], s1 = acc[p][1];
        s0 = fmaf(xv[b], w0.x, s0);     s1 = fmaf(xv[b], w1.x, s1);
        s0 = fmaf(xv[b + 1], w0.y, s0); s1 = fmaf(xv[b + 1], w1.y, s1);
        s0 = fmaf(xv[b + 2], w0.z, s0); s1 = fmaf(xv[b + 2], w1.z, s1);
        s0 = fmaf(xv[b + 3], w0.w, s0); s1 = fmaf(xv[b + 3], w1.w, s1);
        acc[p][0] = s0; acc[p][1] = s1;
      }
    }
  }
  #pragma unroll
  for (int o = 0; o < 2; ++o) {
    const int oc = oc0 + o;
    const float bb = bias[oc];
    float* orow = out + ((size_t)n * 64 + oc) * 36 + oy * 6;
    #pragma unroll
    for (int p = 0; p < 6; ++p)
      orow[p] = fmaxf(acc[p][o] + bb, 0.f);
  }
}

// ---- conv3 v2: block = one frame (256 thr); thread = (oy 0..3, oc 0..63).
// Weights staged transposed in LDS (chunks of 16 in-channels, padded stride 65
// -> conflict-free); x rows via wave-uniform float2 loads (L1 broadcast).
__global__ __launch_bounds__(256) void conv3_kernel(
    const float* __restrict__ a2, const float* __restrict__ w,
    const float* __restrict__ bias, float* __restrict__ out) {
  __shared__ float wTs[144 * 65];   // 37,440 B
  const int n = blockIdx.x;
  const int t = threadIdx.x;
  const int oy = t >> 6;    // 0..3
  const int oc = t & 63;

  float acc[4] = {};
  const float* ab = a2 + (size_t)n * 2304;

  for (int c0 = 0; c0 < 64; c0 += 16) {
    __syncthreads();   // previous chunk fully consumed
    // stage wT[cc*9+r][oc] for cc in [0,16): 9216 elems, 36 per thread,
    // global reads coalesced (consecutive lin -> consecutive rem), LDS writes
    // padded stride 65 -> conflict-free.
    #pragma unroll
    for (int i = 0; i < 36; ++i) {
      const int lin = i * 256 + t;
      const int ocs = lin / 144;
      const int rem = lin - ocs * 144;
      wTs[rem * 65 + ocs] = w[(size_t)ocs * 576 + c0 * 9 + rem];
    }
    __syncthreads();
    for (int cc = 0; cc < 16; ++cc) {
      const float* xb = ab + (c0 + cc) * 36;
      #pragma unroll
      for (int ky = 0; ky < 3; ++ky) {
        const float* xr = xb + (oy + ky) * 6;
        const float2 x01 = *(const float2*)(xr);
        const float2 x23 = *(const float2*)(xr + 2);
        const float2 x45 = *(const float2*)(xr + 4);
        const float xv[6] = {x01.x, x01.y, x23.x, x23.y, x45.x, x45.y};
        const float* wrow = &wTs[(cc * 9 + ky * 3) * 65 + oc];
        const float wk0 = wrow[0], wk1 = wrow[65], wk2 = wrow[130];
        #pragma unroll
        for (int p = 0; p < 4; ++p)
          acc[p] = fmaf(xv[p], wk0,
                   fmaf(xv[p + 1], wk1,
                   fmaf(xv[p + 2], wk2, acc[p])));
      }
    }
  }
  const float bb = bias[oc];
  float* orow = out + ((size_t)n * 64 + oc) * 16 + oy * 4;
  #pragma unroll
  for (int p = 0; p < 4; ++p)
    orow[p] = fmaxf(acc[p] + bb, 0.f);
}

// ---- generic GEMM: C[M,N] = act(A[M,K] @ B[N,K]^T + bias1 (+bias2)) ----
__global__ __launch_bounds__(256) void gemm_bias_kernel(
    const float* __restrict__ A, const float* __restrict__ B,
    const float* __restrict__ bias1, const float* __restrict__ bias2,
    float* __restrict__ C, int M, int N, int K, int relu) {
  __shared__ float As[16][68];
  __shared__ float Bs[16][68];
  const int t = threadIdx.x;
  const int n0 = blockIdx.x * 64;
  const int m0 = blockIdx.y * 64;
  const int ty = t >> 4, tx = t & 15;
  const int sl = t >> 2, kq = (t & 3) * 4;

  float acc[4][4] = {};

  for (int k0 = 0; k0 < K; k0 += 16) {
    float4 av = *(const float4*)(A + (size_t)(m0 + sl) * K + k0 + kq);
    float4 bv = *(const float4*)(B + (size_t)(n0 + sl) * K + k0 + kq);
    As[kq + 0][sl] = av.x; As[kq + 1][sl] = av.y;
    As[kq + 2][sl] = av.z; As[kq + 3][sl] = av.w;
    Bs[kq + 0][sl] = bv.x; Bs[kq + 1][sl] = bv.y;
    Bs[kq + 2][sl] = bv.z; Bs[kq + 3][sl] = bv.w;
    __syncthreads();
    #pragma unroll
    for (int kk = 0; kk < 16; ++kk) {
      float4 a = *(const float4*)&As[kk][ty * 4];
      float4 b = *(const float4*)&Bs[kk][tx * 4];
      float ar[4] = {a.x, a.y, a.z, a.w};
      float br[4] = {b.x, b.y, b.z, b.w};
      #pragma unroll
      for (int i = 0; i < 4; ++i)
        #pragma unroll
        for (int j = 0; j < 4; ++j)
          acc[i][j] = fmaf(ar[i], br[j], acc[i][j]);
    }
    __syncthreads();
  }

  #pragma unroll
  for (int i = 0; i < 4; ++i) {
    int m = m0 + ty * 4 + i;
    #pragma unroll
    for (int j = 0; j < 4; ++j) {
      int n = n0 + tx * 4 + j;
      float v = acc[i][j] + bias1[n];
      if (bias2) v += bias2[n];
      if (relu) v = fmaxf(v, 0.f);
      C[(size_t)m * N + n] = v;
    }
  }
}

// ---- LSTM step (unchanged this round) ----
__global__ __launch_bounds__(256) void lstm_step_kernel(
    const float* __restrict__ gates_pre, const float* __restrict__ wh,
    const float* __restrict__ done, const float* __restrict__ h_prev,
    const float* __restrict__ c_src, float* __restrict__ c_ws,
    float* __restrict__ outs, int step) {
  __shared__ float hs[256 * 33];
  __shared__ float gb[256];
  const int t = threadIdx.x;
  const int bk = blockIdx.x;

  for (int i = 0; i < 32; ++i) {
    float m = 1.f - done[step * 32 + i];
    hs[t * 33 + i] = h_prev[i * 256 + t] * m;
  }
  __syncthreads();

  const int b = t & 31;
  const int g = (t >> 5) & 3;
  const int jj = t >> 7;
  const int j = bk * 2 + jj;
  const int grow = g * 256 + j;
  const float* whr = wh + grow * 256;

  float a0 = 0.f, a1 = 0.f, a2 = 0.f, a3 = 0.f;
  for (int k = 0; k < 256; k += 4) {
    a0 = fmaf(hs[(k + 0) * 33 + b], whr[k + 0], a0);
    a1 = fmaf(hs[(k + 1) * 33 + b], whr[k + 1], a1);
    a2 = fmaf(hs[(k + 2) * 33 + b], whr[k + 2], a2);
    a3 = fmaf(hs[(k + 3) * 33 + b], whr[k + 3], a3);
  }
  float gate = (a0 + a1) + (a2 + a3) + gates_pre[(size_t)(step * 32 + b) * 1024 + grow];
  gb[g * 64 + jj * 32 + b] = gate;
  __syncthreads();

  if (t < 64) {
    int b2 = t & 31, jj2 = t >> 5;
    int j2 = bk * 2 + jj2;
    float iv = gb[0   + jj2 * 32 + b2];
    float fv = gb[64  + jj2 * 32 + b2];
    float gv = gb[128 + jj2 * 32 + b2];
    float ov = gb[192 + jj2 * 32 + b2];
    float m = 1.f - done[step * 32 + b2];
    float c_old = c_src[b2 * 256 + j2] * m;
    float ig = 1.f / (1.f + expf(-iv));
    float fg = 1.f / (1.f + expf(-fv));
    float og = 1.f / (1.f + expf(-ov));
    float cn = fmaf(fg, c_old, ig * tanhf(gv));
    float hn = og * tanhf(cn);
    c_ws[b2 * 256 + j2] = cn;
    outs[(size_t)(step * 32 + b2) * 256 + j2] = hn;
  }
}

// ---- heads (unchanged) ----
__global__ __launch_bounds__(256) void heads_kernel(
    const float* __restrict__ outs, const float* __restrict__ aw,
    const float* __restrict__ ab, const float* __restrict__ cw,
    const float* __restrict__ cb, float* __restrict__ out) {
  __shared__ float rs[8 * 256];
  const int t = threadIdx.x;
  const int r0 = blockIdx.x * 8;
  for (int i = 0; i < 8; ++i)
    rs[i * 256 + t] = outs[(size_t)(r0 + i) * 256 + t];
  __syncthreads();
  int r = t >> 5, c = t & 31;
  if (c < 19) {
    const float* wr = (c < 18) ? (aw + c * 256) : cw;
    float bias = (c < 18) ? ab[c] : cb[0];
    float acc = 0.f;
    for (int k = 0; k < 256; ++k) acc = fmaf(rs[r * 256 + k], wr[k], acc);
    out[(size_t)(r0 + r) * 19 + c] = acc + bias;
  }
}

extern "C" void kernel_launch(void* const* d_in, const int* in_sizes, int n_in,
                              void* d_out, int out_size, void* d_ws, size_t ws_size,
                              hipStream_t stream) {
  const float* x    = (const float*)d_in[0];
  const float* done = (const float*)d_in[1];
  const float* h0   = (const float*)d_in[2];
  const float* c0   = (const float*)d_in[3];
  const float* w1   = (const float*)d_in[4];
  const float* b1   = (const float*)d_in[5];
  const float* w2   = (const float*)d_in[6];
  const float* b2   = (const float*)d_in[7];
  const float* w3   = (const float*)d_in[8];
  const float* b3   = (const float*)d_in[9];
  const float* fcw  = (const float*)d_in[10];
  const float* fcb  = (const float*)d_in[11];
  const float* wi   = (const float*)d_in[12];
  const float* wh   = (const float*)d_in[13];
  const float* bi   = (const float*)d_in[14];
  const float* bh   = (const float*)d_in[15];
  const float* aw   = (const float*)d_in[16];
  const float* abv  = (const float*)d_in[17];
  const float* cw   = (const float*)d_in[18];
  const float* cbv  = (const float*)d_in[19];
  float* out = (float*)d_out;

  const size_t SZ_A1 = 29491200, SZ_A2 = 9437184, SZ_A3 = 4194304;
  const size_t SZ_F = 2097152, SZ_G = 4194304, SZ_O = 1048576, SZ_C = 8192;
  const size_t need = (SZ_A1 + SZ_A2 + SZ_A3 + SZ_F + SZ_G + SZ_O + SZ_C) * 4;
  if (ws_size < need) return;

  float* wsp  = (float*)d_ws;
  float* a1   = wsp;
  float* a2   = a1 + SZ_A1;
  float* a3   = a2 + SZ_A2;
  float* feats= a3 + SZ_A3;
  float* gts  = feats + SZ_F;
  float* outs = gts + SZ_G;
  float* cbuf = outs + SZ_O;

  conv1_kernel<<<4096, 256, 0, stream>>>(x, w1, b1, a1);
  conv2_kernel<<<4096, 192, 0, stream>>>(a1, w2, b2, a2);
  conv3_kernel<<<4096, 256, 0, stream>>>(a2, w3, b3, a3);
  gemm_bias_kernel<<<dim3(8, 64), 256, 0, stream>>>(a3, fcw, fcb, nullptr, feats,
                                                    4096, 512, 1024, 1);
  gemm_bias_kernel<<<dim3(16, 64), 256, 0, stream>>>(feats, wi, bi, bh, gts,
                                                     4096, 1024, 512, 0);
  for (int t = 0; t < 128; ++t) {
    const float* hp = (t == 0) ? h0 : (outs + (size_t)(t - 1) * 8192);
    const float* cs = (t == 0) ? c0 : cbuf;
    lstm_step_kernel<<<128, 256, 0, stream>>>(gts, wh, done, hp, cs, cbuf, outs, t);
  }
  heads_kernel<<<512, 256, 0, stream>>>(outs, aw, abv, cw, cbv, out);
}